// Round 1
// baseline (1389.803 us; speedup 1.0000x reference)
//
#include <hip/hip_runtime.h>

#define B_ 8
#define T_ 2048
#define D_ 1024

// ---------------------------------------------------------------------------
// Kernel 1: causal scores  S[b,t,s] = dot(x[b,t,:], x[b,s,:]) for s-tile <= t-tile.
// Written into the att_weights output region as staging; softmax pass rewrites
// every element, so garbage above the diagonal (within diagonal tiles) is fine.
// 64x64 tile, BK=16, LDS stored k-major ([k][row]) so the inner loop reads
// contiguous float4 (ds_read_b128).
// ---------------------------------------------------------------------------
__global__ __launch_bounds__(256) void scores_kernel(const float* __restrict__ x,
                                                     float* __restrict__ w) {
  const int ts = blockIdx.x;  // s tile
  const int tt = blockIdx.y;  // t tile
  if (ts > tt) return;        // strictly upper tiles never needed
  const int b = blockIdx.z;
  const float* xb = x + (size_t)b * T_ * D_;
  float* wb = w + (size_t)b * T_ * T_;

  __shared__ float As[16][68];
  __shared__ float Bs[16][68];

  const int tid = threadIdx.x;
  const int lrow = tid >> 2;        // 0..63 : row within tile
  const int lk = (tid & 3) << 2;    // 0,4,8,12 : k offset
  const int tx = tid & 15;
  const int ty = tid >> 4;
  const int t0 = tt << 6, s0 = ts << 6;

  float acc[4][4];
#pragma unroll
  for (int i = 0; i < 4; ++i)
#pragma unroll
    for (int j = 0; j < 4; ++j) acc[i][j] = 0.f;

  for (int k0 = 0; k0 < D_; k0 += 16) {
    const float4 av = *(const float4*)(xb + (size_t)(t0 + lrow) * D_ + k0 + lk);
    const float4 bv = *(const float4*)(xb + (size_t)(s0 + lrow) * D_ + k0 + lk);
    __syncthreads();
    As[lk + 0][lrow] = av.x; As[lk + 1][lrow] = av.y;
    As[lk + 2][lrow] = av.z; As[lk + 3][lrow] = av.w;
    Bs[lk + 0][lrow] = bv.x; Bs[lk + 1][lrow] = bv.y;
    Bs[lk + 2][lrow] = bv.z; Bs[lk + 3][lrow] = bv.w;
    __syncthreads();
#pragma unroll
    for (int kk = 0; kk < 16; ++kk) {
      const float4 a = *(const float4*)&As[kk][ty << 2];
      const float4 bq = *(const float4*)&Bs[kk][tx << 2];
      const float ar[4] = {a.x, a.y, a.z, a.w};
      const float br[4] = {bq.x, bq.y, bq.z, bq.w};
#pragma unroll
      for (int i = 0; i < 4; ++i)
#pragma unroll
        for (int j = 0; j < 4; ++j) acc[i][j] = fmaf(ar[i], br[j], acc[i][j]);
    }
  }

#pragma unroll
  for (int i = 0; i < 4; ++i) {
    float4 o;
    o.x = acc[i][0]; o.y = acc[i][1]; o.z = acc[i][2]; o.w = acc[i][3];
    *(float4*)(wb + (size_t)(t0 + (ty << 2) + i) * T_ + s0 + (tx << 2)) = o;
  }
}

// ---------------------------------------------------------------------------
// Kernel 2: row softmax, in place over the weights buffer.
// Row 0: uniform 1/T (reference: all scores -1e9 -> exp(0)=1 each).
// Rows t>=1: softmax over s<t (masked entries underflow to exactly 0 in fp32);
// writes 0 for s>=t. One block per (b,t) row; <=8 values cached per thread.
// ---------------------------------------------------------------------------
__global__ __launch_bounds__(256) void softmax_kernel(float* __restrict__ w) {
  const int row = blockIdx.x;     // b*T + t
  const int t = row & (T_ - 1);
  float* wr = w + (size_t)row * T_;
  const int tid = threadIdx.x;

  if (t == 0) {
    const float u = 1.0f / 2048.0f;
    for (int s = tid; s < T_; s += 256) wr[s] = u;
    return;
  }

  float v[8];
  int n = 0;
  float m = -3.0e38f;
  for (int s = tid; s < t; s += 256) {
    const float val = wr[s];
    v[n++] = val;
    m = fmaxf(m, val);
  }

  __shared__ float red[4];
  const int lane = tid & 63, wave = tid >> 6;
#pragma unroll
  for (int off = 32; off; off >>= 1) m = fmaxf(m, __shfl_xor(m, off));
  if (lane == 0) red[wave] = m;
  __syncthreads();
  m = fmaxf(fmaxf(red[0], red[1]), fmaxf(red[2], red[3]));
  __syncthreads();  // red[] about to be reused

  float l = 0.f;
  for (int k = 0; k < n; ++k) {
    v[k] = __expf(v[k] - m);
    l += v[k];
  }
#pragma unroll
  for (int off = 32; off; off >>= 1) l += __shfl_xor(l, off);
  if (lane == 0) red[wave] = l;
  __syncthreads();
  l = red[0] + red[1] + red[2] + red[3];
  const float inv = 1.0f / l;

  n = 0;
  for (int s = tid; s < t; s += 256) wr[s] = v[n++] * inv;
  for (int s = tid; s < T_; s += 256)
    if (s >= t) wr[s] = 0.f;
}

// ---------------------------------------------------------------------------
// Kernel 3: att_vec[b,t,:] = sum_s W[b,t,s] * x[b,s,:].
// Causal K-loop: s-tiles 0..tile_t (weights are 0 for s>=t so the partial
// diagonal tile is harmless). tile_t==0 loops ALL s-tiles because row 0's
// weights are dense (uniform); rows 1..63 just accumulate zeros there.
// ---------------------------------------------------------------------------
__global__ __launch_bounds__(256) void av_kernel(const float* __restrict__ w,
                                                 const float* __restrict__ x,
                                                 float* __restrict__ out) {
  const int td = blockIdx.x;  // d tile 0..15
  const int tt = blockIdx.y;  // t tile 0..31
  const int b = blockIdx.z;
  const float* wb = w + (size_t)b * T_ * T_;
  const float* xb = x + (size_t)b * T_ * D_;
  float* ob = out + (size_t)b * T_ * D_;

  __shared__ float Aw[16][68];
  __shared__ float Bx[16][68];

  const int tid = threadIdx.x;
  const int tx = tid & 15, ty = tid >> 4;
  const int t0 = tt << 6, d0 = td << 6;
  const int arow = tid >> 2;        // t row within tile (A load)
  const int ak = (tid & 3) << 2;    // k offset (A load)
  const int brow = tid >> 4;        // k row (B load)
  const int bcol = (tid & 15) << 2; // d col (B load)

  const int smax = (tt == 0) ? T_ : ((tt + 1) << 6);

  float acc[4][4];
#pragma unroll
  for (int i = 0; i < 4; ++i)
#pragma unroll
    for (int j = 0; j < 4; ++j) acc[i][j] = 0.f;

  for (int s0k = 0; s0k < smax; s0k += 16) {
    const float4 av = *(const float4*)(wb + (size_t)(t0 + arow) * T_ + s0k + ak);
    const float4 bv = *(const float4*)(xb + (size_t)(s0k + brow) * D_ + d0 + bcol);
    __syncthreads();
    Aw[ak + 0][arow] = av.x; Aw[ak + 1][arow] = av.y;
    Aw[ak + 2][arow] = av.z; Aw[ak + 3][arow] = av.w;
    *(float4*)&Bx[brow][bcol] = bv;
    __syncthreads();
#pragma unroll
    for (int kk = 0; kk < 16; ++kk) {
      const float4 a = *(const float4*)&Aw[kk][ty << 2];
      const float4 bq = *(const float4*)&Bx[kk][tx << 2];
      const float ar[4] = {a.x, a.y, a.z, a.w};
      const float br[4] = {bq.x, bq.y, bq.z, bq.w};
#pragma unroll
      for (int i = 0; i < 4; ++i)
#pragma unroll
        for (int j = 0; j < 4; ++j) acc[i][j] = fmaf(ar[i], br[j], acc[i][j]);
    }
  }

#pragma unroll
  for (int i = 0; i < 4; ++i) {
    float4 o;
    o.x = acc[i][0]; o.y = acc[i][1]; o.z = acc[i][2]; o.w = acc[i][3];
    *(float4*)(ob + (size_t)(t0 + (ty << 2) + i) * D_ + d0 + (tx << 2)) = o;
  }
}

// ---------------------------------------------------------------------------
extern "C" void kernel_launch(void* const* d_in, const int* in_sizes, int n_in,
                              void* d_out, int out_size, void* d_ws, size_t ws_size,
                              hipStream_t stream) {
  const float* x = (const float*)d_in[0];
  float* att_vec = (float*)d_out;                       // [B,T,D] output 0
  float* w = (float*)d_out + (size_t)B_ * T_ * D_;      // [B,T,T] output 1 (also score staging)

  scores_kernel<<<dim3(32, 32, B_), 256, 0, stream>>>(x, w);
  softmax_kernel<<<dim3(B_ * T_), 256, 0, stream>>>(w);
  av_kernel<<<dim3(16, 32, B_), 256, 0, stream>>>(w, x, att_vec);
}

// Round 2
// 640.134 us; speedup vs baseline: 2.1711x; 2.1711x over previous
//
#include <hip/hip_runtime.h>

#define B_ 8
#define T_ 2048
#define D_ 1024

typedef __attribute__((ext_vector_type(8))) short bf16x8;
typedef __attribute__((ext_vector_type(4))) float f32x4;
typedef __attribute__((ext_vector_type(8))) unsigned short u16x8;
typedef __attribute__((ext_vector_type(4))) unsigned short u16x4;

__device__ __forceinline__ unsigned short f2bf(float f) {
  union { float f; unsigned u; } v; v.f = f;
  unsigned r = v.u + 0x7FFFu + ((v.u >> 16) & 1u);  // RNE (inputs are finite gaussians)
  return (unsigned short)(r >> 16);
}
__device__ __forceinline__ float bf2f(unsigned short h) {
  union { unsigned u; float f; } v; v.u = ((unsigned)h) << 16; return v.f;
}

// async global->LDS, 16B per lane; LDS dest = wave-uniform base + lane*16
__device__ __forceinline__ void gl2lds16(const void* g, void* l) {
  __builtin_amdgcn_global_load_lds(
      (__attribute__((address_space(1))) void*)g,
      (__attribute__((address_space(3))) void*)l, 16, 0, 0);
}

// ---------------------------------------------------------------------------
// Prep: x fp32 -> x_hi/x_lo bf16 (row-major [b,t,d]) AND transposed xT_hi/xT_lo
// ([b,d,t], for the AV GEMM's B operand which needs k=s contiguous).
// 64x64 tiles through LDS for the transpose.
// ---------------------------------------------------------------------------
__global__ __launch_bounds__(256) void prep_kernel(
    const float* __restrict__ x,
    unsigned short* __restrict__ xh, unsigned short* __restrict__ xl,
    unsigned short* __restrict__ xth, unsigned short* __restrict__ xtl) {
  const int b = blockIdx.z;
  const int t0 = blockIdx.y << 6;
  const int d0 = blockIdx.x << 6;
  __shared__ unsigned short th[64][68];
  __shared__ unsigned short tl[64][68];
  const int tid = threadIdx.x;
  const int row = tid & 63, cq = tid >> 6;
  const size_t xoff = ((size_t)b * T_ + t0 + row) * D_ + d0;
#pragma unroll
  for (int c = 0; c < 4; ++c) {
    const int col = (cq << 4) + (c << 2);
    const float4 v = *(const float4*)(x + xoff + col);
    const unsigned short h0 = f2bf(v.x), h1 = f2bf(v.y), h2 = f2bf(v.z), h3 = f2bf(v.w);
    const unsigned short l0 = f2bf(v.x - bf2f(h0)), l1 = f2bf(v.y - bf2f(h1));
    const unsigned short l2 = f2bf(v.z - bf2f(h2)), l3 = f2bf(v.w - bf2f(h3));
    u16x4 hv = {h0, h1, h2, h3}, lv = {l0, l1, l2, l3};
    *(u16x4*)(xh + xoff + col) = hv;
    *(u16x4*)(xl + xoff + col) = lv;
    th[col + 0][row] = h0; th[col + 1][row] = h1;
    th[col + 2][row] = h2; th[col + 3][row] = h3;
    tl[col + 0][row] = l0; tl[col + 1][row] = l1;
    tl[col + 2][row] = l2; tl[col + 3][row] = l3;
  }
  __syncthreads();
  const size_t toff = ((size_t)b * D_ + d0 + row) * T_ + t0;
#pragma unroll
  for (int c = 0; c < 4; ++c) {
    const int col = (cq << 4) + (c << 2);
    u16x4 hv = *(const u16x4*)&th[row][col];
    u16x4 lv = *(const u16x4*)&tl[row][col];
    *(u16x4*)(xth + toff + col) = hv;
    *(u16x4*)(xtl + toff + col) = lv;
  }
}

// ---------------------------------------------------------------------------
// Scores: S = x . x^T (causal tiles only), split-precision bf16 MFMA:
// S = Ah.Bh + Ah.Bl + Al.Bh  (rel err ~2^-17). 128x128 block tile, BK=32,
// global_load_lds(16B) staging, 4 waves of 64x64 via 16x16x32 MFMA.
// Raw scores go to the att_weights output region (softmax rewrites all).
// ---------------------------------------------------------------------------
__global__ __launch_bounds__(256) void scores_mfma(
    const unsigned short* __restrict__ xh, const unsigned short* __restrict__ xl,
    float* __restrict__ w) {
  const int ts = blockIdx.x, tt = blockIdx.y;
  if (ts > tt) return;  // strictly-upper tiles never read by softmax
  const int b = blockIdx.z;
  const int t0 = tt << 7, s0 = ts << 7;
  __shared__ unsigned short Ah[128 * 32];
  __shared__ unsigned short Al[128 * 32];
  __shared__ unsigned short Bh[128 * 32];
  __shared__ unsigned short Bl[128 * 32];
  const int tid = threadIdx.x;
  const int lane = tid & 63, wv = tid >> 6;
  const int wr = (wv >> 1) << 6, wc = (wv & 1) << 6;
  const int quad = lane >> 4, r16 = lane & 15;
  const size_t xb = (size_t)b * T_ * D_;

  f32x4 acc[4][4];
#pragma unroll
  for (int i = 0; i < 4; ++i)
#pragma unroll
    for (int j = 0; j < 4; ++j) acc[i][j] = (f32x4){0.f, 0.f, 0.f, 0.f};

  for (int k0 = 0; k0 < D_; k0 += 32) {
    __syncthreads();
#pragma unroll
    for (int i = 0; i < 2; ++i) {
      const int cc = (wv << 7) + (i << 6) + lane;  // 16B chunk id 0..511
      const int row = cc >> 2, q = cc & 3;
      const int ldsoff = (((wv << 7) + (i << 6)) << 3);  // shorts; wave-uniform
      const size_t ga = xb + (size_t)(t0 + row) * D_ + k0 + (q << 3);
      const size_t gb = xb + (size_t)(s0 + row) * D_ + k0 + (q << 3);
      gl2lds16(xh + ga, &Ah[ldsoff]);
      gl2lds16(xl + ga, &Al[ldsoff]);
      gl2lds16(xh + gb, &Bh[ldsoff]);
      gl2lds16(xl + gb, &Bl[ldsoff]);
    }
    __syncthreads();
    bf16x8 ah[4], al[4], bh[4], bl[4];
#pragma unroll
    for (int i = 0; i < 4; ++i) {
      const int ra = ((wr + (i << 4) + r16) << 5) + (quad << 3);
      const int rb = ((wc + (i << 4) + r16) << 5) + (quad << 3);
      ah[i] = *(const bf16x8*)&Ah[ra];
      al[i] = *(const bf16x8*)&Al[ra];
      bh[i] = *(const bf16x8*)&Bh[rb];
      bl[i] = *(const bf16x8*)&Bl[rb];
    }
#pragma unroll
    for (int i = 0; i < 4; ++i)
#pragma unroll
      for (int j = 0; j < 4; ++j) {
        acc[i][j] = __builtin_amdgcn_mfma_f32_16x16x32_bf16(ah[i], bh[j], acc[i][j], 0, 0, 0);
        acc[i][j] = __builtin_amdgcn_mfma_f32_16x16x32_bf16(ah[i], bl[j], acc[i][j], 0, 0, 0);
        acc[i][j] = __builtin_amdgcn_mfma_f32_16x16x32_bf16(al[i], bh[j], acc[i][j], 0, 0, 0);
      }
  }

  float* wb = w + (size_t)b * T_ * T_;
#pragma unroll
  for (int i = 0; i < 4; ++i)
#pragma unroll
    for (int j = 0; j < 4; ++j) {
      const int rr = t0 + wr + (i << 4) + (quad << 2);
      const int cc = s0 + wc + (j << 4) + r16;
#pragma unroll
      for (int rg = 0; rg < 4; ++rg)
        wb[(size_t)(rr + rg) * T_ + cc] = acc[i][j][rg];
    }
}

// ---------------------------------------------------------------------------
// Row softmax in place (unchanged from passing round-1 version).
// ---------------------------------------------------------------------------
__global__ __launch_bounds__(256) void softmax_kernel(float* __restrict__ w) {
  const int row = blockIdx.x;  // b*T + t
  const int t = row & (T_ - 1);
  float* wr = w + (size_t)row * T_;
  const int tid = threadIdx.x;

  if (t == 0) {
    const float u = 1.0f / 2048.0f;
    for (int s = tid; s < T_; s += 256) wr[s] = u;
    return;
  }

  float v[8];
  int n = 0;
  float m = -3.0e38f;
  for (int s = tid; s < t; s += 256) {
    const float val = wr[s];
    v[n++] = val;
    m = fmaxf(m, val);
  }

  __shared__ float red[4];
  const int lane = tid & 63, wave = tid >> 6;
#pragma unroll
  for (int off = 32; off; off >>= 1) m = fmaxf(m, __shfl_xor(m, off));
  if (lane == 0) red[wave] = m;
  __syncthreads();
  m = fmaxf(fmaxf(red[0], red[1]), fmaxf(red[2], red[3]));
  __syncthreads();

  float l = 0.f;
  for (int k = 0; k < n; ++k) {
    v[k] = __expf(v[k] - m);
    l += v[k];
  }
#pragma unroll
  for (int off = 32; off; off >>= 1) l += __shfl_xor(l, off);
  if (lane == 0) red[wave] = l;
  __syncthreads();
  l = red[0] + red[1] + red[2] + red[3];
  const float inv = 1.0f / l;

  n = 0;
  for (int s = tid; s < t; s += 256) wr[s] = v[n++] * inv;
  for (int s = tid; s < T_; s += 256)
    if (s >= t) wr[s] = 0.f;
}

// ---------------------------------------------------------------------------
// AV: out = W . x. A = W (fp32 -> single bf16 in staging; W in [0,1], err tiny),
// B = xT_hi/xT_lo (2 products recover x exactly). Tile 64(t) x 256(d), BK=32.
// Causal K range; tt==0 runs full T for the dense uniform row 0 (zero weights
// elsewhere make it correct for t=1..63).
// ---------------------------------------------------------------------------
__global__ __launch_bounds__(256) void av_mfma(
    const float* __restrict__ w,
    const unsigned short* __restrict__ xth, const unsigned short* __restrict__ xtl,
    float* __restrict__ out) {
  const int td = blockIdx.x;  // 0..3
  const int tt = blockIdx.y;  // 0..31
  const int b = blockIdx.z;
  const int t0 = tt << 6, d0 = td << 8;
  __shared__ unsigned short Aw[64 * 32];
  __shared__ unsigned short Bh[256 * 32];
  __shared__ unsigned short Bl[256 * 32];
  const int tid = threadIdx.x;
  const int lane = tid & 63, wv = tid >> 6;
  const int quad = lane >> 4, r16 = lane & 15;
  const float* wb = w + (size_t)b * T_ * T_;
  const size_t xtb = (size_t)b * D_ * T_;
  const int smax = (tt == 0) ? T_ : (t0 + 64);
  const int arow = tid >> 2, aq = tid & 3;

  f32x4 acc[4][4];
#pragma unroll
  for (int i = 0; i < 4; ++i)
#pragma unroll
    for (int j = 0; j < 4; ++j) acc[i][j] = (f32x4){0.f, 0.f, 0.f, 0.f};

  for (int s0 = 0; s0 < smax; s0 += 32) {
    __syncthreads();
    {
      const float* g = wb + (size_t)(t0 + arow) * T_ + s0 + (aq << 3);
      const float4 v0 = ((const float4*)g)[0];
      const float4 v1 = ((const float4*)g)[1];
      u16x8 hv = {f2bf(v0.x), f2bf(v0.y), f2bf(v0.z), f2bf(v0.w),
                  f2bf(v1.x), f2bf(v1.y), f2bf(v1.z), f2bf(v1.w)};
      *(u16x8*)&Aw[(arow << 5) + (aq << 3)] = hv;
    }
#pragma unroll
    for (int i = 0; i < 4; ++i) {
      const int cc = (wv << 8) + (i << 6) + lane;  // 0..1023
      const int row = cc >> 2, q = cc & 3;
      const int ldsoff = (((wv << 8) + (i << 6)) << 3);
      const size_t gaddr = xtb + (size_t)(d0 + row) * T_ + s0 + (q << 3);
      gl2lds16(xth + gaddr, &Bh[ldsoff]);
      gl2lds16(xtl + gaddr, &Bl[ldsoff]);
    }
    __syncthreads();
    bf16x8 a[4], bh[4], bl[4];
#pragma unroll
    for (int i = 0; i < 4; ++i)
      a[i] = *(const bf16x8*)&Aw[(((i << 4) + r16) << 5) + (quad << 3)];
#pragma unroll
    for (int j = 0; j < 4; ++j) {
      const int rb = (((wv << 6) + (j << 4) + r16) << 5) + (quad << 3);
      bh[j] = *(const bf16x8*)&Bh[rb];
      bl[j] = *(const bf16x8*)&Bl[rb];
    }
#pragma unroll
    for (int i = 0; i < 4; ++i)
#pragma unroll
      for (int j = 0; j < 4; ++j) {
        acc[i][j] = __builtin_amdgcn_mfma_f32_16x16x32_bf16(a[i], bh[j], acc[i][j], 0, 0, 0);
        acc[i][j] = __builtin_amdgcn_mfma_f32_16x16x32_bf16(a[i], bl[j], acc[i][j], 0, 0, 0);
      }
  }

  float* ob = out + (size_t)b * T_ * D_;
#pragma unroll
  for (int i = 0; i < 4; ++i)
#pragma unroll
    for (int j = 0; j < 4; ++j) {
      const int rr = t0 + (i << 4) + (quad << 2);
      const int cc = d0 + (wv << 6) + (j << 4) + r16;
#pragma unroll
      for (int rg = 0; rg < 4; ++rg)
        ob[(size_t)(rr + rg) * D_ + cc] = acc[i][j][rg];
    }
}

// ---------------------------------------------------------------------------
extern "C" void kernel_launch(void* const* d_in, const int* in_sizes, int n_in,
                              void* d_out, int out_size, void* d_ws, size_t ws_size,
                              hipStream_t stream) {
  const float* x = (const float*)d_in[0];
  float* att_vec = (float*)d_out;                   // [B,T,D] output 0
  float* w = (float*)d_out + (size_t)B_ * T_ * D_;  // [B,T,T] output 1

  // x_hi/x_lo staged inside the att_vec output region (exact 67 MB fit).
  // av_mfma never reads them, so its out-writes can't race a reader.
  unsigned short* xh = (unsigned short*)att_vec;
  unsigned short* xl = xh + (size_t)B_ * T_ * D_;
  // transposed copies in workspace (67 MB).
  unsigned short* xth = (unsigned short*)d_ws;
  unsigned short* xtl = xth + (size_t)B_ * D_ * T_;

  prep_kernel<<<dim3(D_ / 64, T_ / 64, B_), 256, 0, stream>>>(x, xh, xl, xth, xtl);
  scores_mfma<<<dim3(16, 16, B_), 256, 0, stream>>>(xh, xl, w);
  softmax_kernel<<<dim3(B_ * T_), 256, 0, stream>>>(w);
  av_mfma<<<dim3(4, 32, B_), 256, 0, stream>>>(w, xth, xtl, att_vec);
}

// Round 3
// 589.734 us; speedup vs baseline: 2.3567x; 1.0855x over previous
//
#include <hip/hip_runtime.h>

#define B_ 8
#define T_ 2048
#define D_ 1024

typedef __attribute__((ext_vector_type(8))) short bf16x8;
typedef __attribute__((ext_vector_type(4))) float f32x4;
typedef __attribute__((ext_vector_type(8))) unsigned short u16x8;
typedef __attribute__((ext_vector_type(4))) unsigned short u16x4;

__device__ __forceinline__ unsigned short f2bf(float f) {
  union { float f; unsigned u; } v; v.f = f;
  unsigned r = v.u + 0x7FFFu + ((v.u >> 16) & 1u);  // RNE (finite inputs only)
  return (unsigned short)(r >> 16);
}
__device__ __forceinline__ float bf2f(unsigned short h) {
  union { unsigned u; float f; } v; v.u = ((unsigned)h) << 16; return v.f;
}

// async global->LDS, 16B/lane; LDS dest = wave-uniform base + lane*16
__device__ __forceinline__ void gl2lds16(const void* g, void* l) {
  __builtin_amdgcn_global_load_lds(
      (__attribute__((address_space(1))) void*)g,
      (__attribute__((address_space(3))) void*)l, 16, 0, 0);
}

// ---------------------------------------------------------------------------
// Prep: x fp32 -> x_hi/x_lo bf16 (row-major) + transposed xT_hi/xT_lo [b,d,t].
// ---------------------------------------------------------------------------
__global__ __launch_bounds__(256) void prep_kernel(
    const float* __restrict__ x,
    unsigned short* __restrict__ xh, unsigned short* __restrict__ xl,
    unsigned short* __restrict__ xth, unsigned short* __restrict__ xtl) {
  const int b = blockIdx.z;
  const int t0 = blockIdx.y << 6;
  const int d0 = blockIdx.x << 6;
  __shared__ unsigned short th[64][68];
  __shared__ unsigned short tl[64][68];
  const int tid = threadIdx.x;
  const int row = tid & 63, cq = tid >> 6;
  const size_t xoff = ((size_t)b * T_ + t0 + row) * D_ + d0;
#pragma unroll
  for (int c = 0; c < 4; ++c) {
    const int col = (cq << 4) + (c << 2);
    const float4 v = *(const float4*)(x + xoff + col);
    const unsigned short h0 = f2bf(v.x), h1 = f2bf(v.y), h2 = f2bf(v.z), h3 = f2bf(v.w);
    const unsigned short l0 = f2bf(v.x - bf2f(h0)), l1 = f2bf(v.y - bf2f(h1));
    const unsigned short l2 = f2bf(v.z - bf2f(h2)), l3 = f2bf(v.w - bf2f(h3));
    u16x4 hv = {h0, h1, h2, h3}, lv = {l0, l1, l2, l3};
    *(u16x4*)(xh + xoff + col) = hv;
    *(u16x4*)(xl + xoff + col) = lv;
    th[col + 0][row] = h0; th[col + 1][row] = h1;
    th[col + 2][row] = h2; th[col + 3][row] = h3;
    tl[col + 0][row] = l0; tl[col + 1][row] = l1;
    tl[col + 2][row] = l2; tl[col + 3][row] = l3;
  }
  __syncthreads();
  const size_t toff = ((size_t)b * D_ + d0 + row) * T_ + t0;
#pragma unroll
  for (int c = 0; c < 4; ++c) {
    const int col = (cq << 4) + (c << 2);
    u16x4 hv = *(const u16x4*)&th[row][col];
    u16x4 lv = *(const u16x4*)&tl[row][col];
    *(u16x4*)(xth + toff + col) = hv;
    *(u16x4*)(xtl + toff + col) = lv;
  }
}

// ---------------------------------------------------------------------------
// Scores: S = x.x^T, causal tiles, 3-product split-bf16 MFMA (err ~2^-17).
// 128x128 tile, BK=32, global_load_lds staging. (unchanged from round 2)
// ---------------------------------------------------------------------------
__global__ __launch_bounds__(256) void scores_mfma(
    const unsigned short* __restrict__ xh, const unsigned short* __restrict__ xl,
    float* __restrict__ w) {
  const int ts = blockIdx.x, tt = blockIdx.y;
  if (ts > tt) return;
  const int b = blockIdx.z;
  const int t0 = tt << 7, s0 = ts << 7;
  __shared__ unsigned short Ah[128 * 32];
  __shared__ unsigned short Al[128 * 32];
  __shared__ unsigned short Bh[128 * 32];
  __shared__ unsigned short Bl[128 * 32];
  const int tid = threadIdx.x;
  const int lane = tid & 63, wv = tid >> 6;
  const int wr = (wv >> 1) << 6, wc = (wv & 1) << 6;
  const int quad = lane >> 4, r16 = lane & 15;
  const size_t xb = (size_t)b * T_ * D_;

  f32x4 acc[4][4];
#pragma unroll
  for (int i = 0; i < 4; ++i)
#pragma unroll
    for (int j = 0; j < 4; ++j) acc[i][j] = (f32x4){0.f, 0.f, 0.f, 0.f};

  for (int k0 = 0; k0 < D_; k0 += 32) {
    __syncthreads();
#pragma unroll
    for (int i = 0; i < 2; ++i) {
      const int cc = (wv << 7) + (i << 6) + lane;
      const int row = cc >> 2, q = cc & 3;
      const int ldsoff = (((wv << 7) + (i << 6)) << 3);
      const size_t ga = xb + (size_t)(t0 + row) * D_ + k0 + (q << 3);
      const size_t gb = xb + (size_t)(s0 + row) * D_ + k0 + (q << 3);
      gl2lds16(xh + ga, &Ah[ldsoff]);
      gl2lds16(xl + ga, &Al[ldsoff]);
      gl2lds16(xh + gb, &Bh[ldsoff]);
      gl2lds16(xl + gb, &Bl[ldsoff]);
    }
    __syncthreads();
    bf16x8 ah[4], al[4], bh[4], bl[4];
#pragma unroll
    for (int i = 0; i < 4; ++i) {
      const int ra = ((wr + (i << 4) + r16) << 5) + (quad << 3);
      const int rb = ((wc + (i << 4) + r16) << 5) + (quad << 3);
      ah[i] = *(const bf16x8*)&Ah[ra];
      al[i] = *(const bf16x8*)&Al[ra];
      bh[i] = *(const bf16x8*)&Bh[rb];
      bl[i] = *(const bf16x8*)&Bl[rb];
    }
#pragma unroll
    for (int i = 0; i < 4; ++i)
#pragma unroll
      for (int j = 0; j < 4; ++j) {
        acc[i][j] = __builtin_amdgcn_mfma_f32_16x16x32_bf16(ah[i], bh[j], acc[i][j], 0, 0, 0);
        acc[i][j] = __builtin_amdgcn_mfma_f32_16x16x32_bf16(ah[i], bl[j], acc[i][j], 0, 0, 0);
        acc[i][j] = __builtin_amdgcn_mfma_f32_16x16x32_bf16(al[i], bh[j], acc[i][j], 0, 0, 0);
      }
  }

  float* wb = w + (size_t)b * T_ * T_;
#pragma unroll
  for (int i = 0; i < 4; ++i)
#pragma unroll
    for (int j = 0; j < 4; ++j) {
      const int rr = t0 + wr + (i << 4) + (quad << 2);
      const int cc = s0 + wc + (j << 4) + r16;
#pragma unroll
      for (int rg = 0; rg < 4; ++rg)
        wb[(size_t)(rr + rg) * T_ + cc] = acc[i][j][rg];
    }
}

// ---------------------------------------------------------------------------
// Softmax: one WAVE per row, 32 values/lane in registers (fixed trip count —
// no scratch). Masked slots get -1e30 -> exp underflows to exactly 0.
// Optionally emits a bf16 copy of W for the AV GEMM.
// ---------------------------------------------------------------------------
template <bool EMIT_BF16>
__global__ __launch_bounds__(256) void softmax_kernel(float* __restrict__ w,
                                                      unsigned short* __restrict__ wb16) {
  const int row = (blockIdx.x << 2) + (threadIdx.x >> 6);  // b*T + t
  const int t = row & (T_ - 1);
  const int lane = threadIdx.x & 63;
  float* wr = w + (size_t)row * T_;
  unsigned short* wbr = wb16 + (size_t)row * T_;

  if (t == 0) {
    const float u = 1.0f / 2048.0f;
    const unsigned short ub = f2bf(u);
#pragma unroll
    for (int k = 0; k < 32; ++k) {
      wr[lane + (k << 6)] = u;
      if (EMIT_BF16) wbr[lane + (k << 6)] = ub;
    }
    return;
  }

  float v[32];
  float m = -3.0e38f;
#pragma unroll
  for (int k = 0; k < 32; ++k) {
    const int s = lane + (k << 6);
    v[k] = (s < t) ? wr[s] : -1.0e30f;
    m = fmaxf(m, v[k]);
  }
#pragma unroll
  for (int off = 32; off; off >>= 1) m = fmaxf(m, __shfl_xor(m, off));

  float l = 0.f;
#pragma unroll
  for (int k = 0; k < 32; ++k) {
    v[k] = __expf(v[k] - m);  // masked slots: exp(-huge) == 0.0f exactly
    l += v[k];
  }
#pragma unroll
  for (int off = 32; off; off >>= 1) l += __shfl_xor(l, off);
  const float inv = 1.0f / l;

#pragma unroll
  for (int k = 0; k < 32; ++k) {
    const float o = v[k] * inv;
    const int s = lane + (k << 6);
    wr[s] = o;
    if (EMIT_BF16) wbr[s] = f2bf(o);
  }
}

// ---------------------------------------------------------------------------
// AV: out = W.x  (A = W bf16, B = xT hi/lo, 2 products). 128(t)x128(d) tile,
// BK=32, all operands via global_load_lds. Heavy t-tiles scheduled first.
// WB16 path: A staged straight from the bf16 W buffer (no VALU convert).
// Fallback: stage fp32 W through registers + convert (round-2 style).
// ---------------------------------------------------------------------------
template <bool USE_WB16>
__global__ __launch_bounds__(256) void av_mfma(
    const float* __restrict__ w, const unsigned short* __restrict__ wb16,
    const unsigned short* __restrict__ xth, const unsigned short* __restrict__ xtl,
    float* __restrict__ out) {
  const int y = blockIdx.y;
  const int tt = (y == 0) ? 0 : (16 - y);  // heavy tiles (tt=0,15,14,...) first
  const int td = blockIdx.x;               // 0..7
  const int b = blockIdx.z;
  const int t0 = tt << 7, d0 = td << 7;
  __shared__ unsigned short Aw[128 * 32];
  __shared__ unsigned short Bh[128 * 32];
  __shared__ unsigned short Bl[128 * 32];
  const int tid = threadIdx.x;
  const int lane = tid & 63, wv = tid >> 6;
  const int wr = (wv >> 1) << 6, wc = (wv & 1) << 6;
  const int quad = lane >> 4, r16 = lane & 15;
  const size_t xtb = (size_t)b * D_ * T_;
  const size_t wrowb = (size_t)b * T_ * T_;
  const int smax = (tt == 0) ? T_ : (t0 + 128);

  f32x4 acc[4][4];
#pragma unroll
  for (int i = 0; i < 4; ++i)
#pragma unroll
    for (int j = 0; j < 4; ++j) acc[i][j] = (f32x4){0.f, 0.f, 0.f, 0.f};

  for (int s0 = 0; s0 < smax; s0 += 32) {
    __syncthreads();
    if (USE_WB16) {
#pragma unroll
      for (int i = 0; i < 2; ++i) {
        const int cc = (wv << 7) + (i << 6) + lane;  // 0..511
        const int row = cc >> 2, q = cc & 3;
        const int ldsoff = (((wv << 7) + (i << 6)) << 3);
        gl2lds16(wb16 + wrowb + (size_t)(t0 + row) * T_ + s0 + (q << 3), &Aw[ldsoff]);
      }
    } else {
      const int row = tid >> 1, cs = (tid & 1) << 4;
      const float* g = w + wrowb + (size_t)(t0 + row) * T_ + s0 + cs;
      const float4 v0 = ((const float4*)g)[0];
      const float4 v1 = ((const float4*)g)[1];
      const float4 v2 = ((const float4*)g)[2];
      const float4 v3 = ((const float4*)g)[3];
      u16x8 p0 = {f2bf(v0.x), f2bf(v0.y), f2bf(v0.z), f2bf(v0.w),
                  f2bf(v1.x), f2bf(v1.y), f2bf(v1.z), f2bf(v1.w)};
      u16x8 p1 = {f2bf(v2.x), f2bf(v2.y), f2bf(v2.z), f2bf(v2.w),
                  f2bf(v3.x), f2bf(v3.y), f2bf(v3.z), f2bf(v3.w)};
      *(u16x8*)&Aw[(row << 5) + cs] = p0;
      *(u16x8*)&Aw[(row << 5) + cs + 8] = p1;
    }
#pragma unroll
    for (int i = 0; i < 2; ++i) {
      const int cc = (wv << 7) + (i << 6) + lane;
      const int row = cc >> 2, q = cc & 3;
      const int ldsoff = (((wv << 7) + (i << 6)) << 3);
      const size_t gaddr = xtb + (size_t)(d0 + row) * T_ + s0 + (q << 3);
      gl2lds16(xth + gaddr, &Bh[ldsoff]);
      gl2lds16(xtl + gaddr, &Bl[ldsoff]);
    }
    __syncthreads();
    bf16x8 a[4], bh[4], bl[4];
#pragma unroll
    for (int i = 0; i < 4; ++i)
      a[i] = *(const bf16x8*)&Aw[((wr + (i << 4) + r16) << 5) + (quad << 3)];
#pragma unroll
    for (int j = 0; j < 4; ++j) {
      const int rb = ((wc + (j << 4) + r16) << 5) + (quad << 3);
      bh[j] = *(const bf16x8*)&Bh[rb];
      bl[j] = *(const bf16x8*)&Bl[rb];
    }
#pragma unroll
    for (int i = 0; i < 4; ++i)
#pragma unroll
      for (int j = 0; j < 4; ++j) {
        acc[i][j] = __builtin_amdgcn_mfma_f32_16x16x32_bf16(a[i], bh[j], acc[i][j], 0, 0, 0);
        acc[i][j] = __builtin_amdgcn_mfma_f32_16x16x32_bf16(a[i], bl[j], acc[i][j], 0, 0, 0);
      }
  }

  float* ob = out + (size_t)b * T_ * D_;
#pragma unroll
  for (int i = 0; i < 4; ++i)
#pragma unroll
    for (int j = 0; j < 4; ++j) {
      const int rr = t0 + wr + (i << 4) + (quad << 2);
      const int cc = d0 + wc + (j << 4) + r16;
#pragma unroll
      for (int rg = 0; rg < 4; ++rg)
        ob[(size_t)(rr + rg) * D_ + cc] = acc[i][j][rg];
    }
}

// ---------------------------------------------------------------------------
extern "C" void kernel_launch(void* const* d_in, const int* in_sizes, int n_in,
                              void* d_out, int out_size, void* d_ws, size_t ws_size,
                              hipStream_t stream) {
  const float* x = (const float*)d_in[0];
  float* att_vec = (float*)d_out;                   // [B,T,D] output 0
  float* w = (float*)d_out + (size_t)B_ * T_ * D_;  // [B,T,T] output 1

  // x_hi/x_lo staged in the att_vec region (read only by scores; av overwrites later)
  unsigned short* xh = (unsigned short*)att_vec;
  unsigned short* xl = xh + (size_t)B_ * T_ * D_;
  // workspace: xT hi/lo (67 MB) + optional bf16 W (67 MB)
  unsigned short* xth = (unsigned short*)d_ws;
  unsigned short* xtl = xth + (size_t)B_ * D_ * T_;
  unsigned short* wb16 = xtl + (size_t)B_ * D_ * T_;
  const size_t need = (size_t)4 * B_ * D_ * T_ + (size_t)2 * B_ * T_ * T_;
  const bool use_wb16 = (ws_size >= need);

  prep_kernel<<<dim3(D_ / 64, T_ / 64, B_), 256, 0, stream>>>(x, xh, xl, xth, xtl);
  scores_mfma<<<dim3(16, 16, B_), 256, 0, stream>>>(xh, xl, w);
  if (use_wb16) {
    softmax_kernel<true><<<dim3(B_ * T_ / 4), 256, 0, stream>>>(w, wb16);
    av_mfma<true><<<dim3(8, 16, B_), 256, 0, stream>>>(w, wb16, xth, xtl, att_vec);
  } else {
    softmax_kernel<false><<<dim3(B_ * T_ / 4), 256, 0, stream>>>(w, wb16);
    av_mfma<false><<<dim3(8, 16, B_), 256, 0, stream>>>(w, wb16, xth, xtl, att_vec);
  }
}

// Round 4
// 581.458 us; speedup vs baseline: 2.3902x; 1.0142x over previous
//
#include <hip/hip_runtime.h>

#define B_ 8
#define T_ 2048
#define D_ 1024

typedef __attribute__((ext_vector_type(8))) short bf16x8;
typedef __attribute__((ext_vector_type(8))) _Float16 f16x8;
typedef __attribute__((ext_vector_type(4))) float f32x4;
typedef __attribute__((ext_vector_type(8))) unsigned short u16x8;
typedef __attribute__((ext_vector_type(4))) unsigned short u16x4;

__device__ __forceinline__ unsigned short f2bf(float f) {
  union { float f; unsigned u; } v; v.f = f;
  unsigned r = v.u + 0x7FFFu + ((v.u >> 16) & 1u);  // RNE (finite inputs only)
  return (unsigned short)(r >> 16);
}
__device__ __forceinline__ float bf2f(unsigned short h) {
  union { unsigned u; float f; } v; v.u = ((unsigned)h) << 16; return v.f;
}
__device__ __forceinline__ unsigned short f2h(float f) {
  union { _Float16 h; unsigned short u; } v; v.h = (_Float16)f; return v.u;
}

// async global->LDS, 16B/lane; LDS dest = wave-uniform base + lane*16
__device__ __forceinline__ void gl2lds16(const void* g, void* l) {
  __builtin_amdgcn_global_load_lds(
      (__attribute__((address_space(1))) void*)g,
      (__attribute__((address_space(3))) void*)l, 16, 0, 0);
}

// ---------------------------------------------------------------------------
// Prep: x fp32 -> x_hi/x_lo bf16 (row-major, for scores) + xT fp16 [b,d,t]
// (single plane, for av's B operand).
// ---------------------------------------------------------------------------
__global__ __launch_bounds__(256) void prep_kernel(
    const float* __restrict__ x,
    unsigned short* __restrict__ xh, unsigned short* __restrict__ xl,
    unsigned short* __restrict__ xth) {
  const int b = blockIdx.z;
  const int t0 = blockIdx.y << 6;
  const int d0 = blockIdx.x << 6;
  __shared__ unsigned short tf[64][68];  // fp16 bits, transpose staging
  const int tid = threadIdx.x;
  const int row = tid & 63, cq = tid >> 6;
  const size_t xoff = ((size_t)b * T_ + t0 + row) * D_ + d0;
#pragma unroll
  for (int c = 0; c < 4; ++c) {
    const int col = (cq << 4) + (c << 2);
    const float4 v = *(const float4*)(x + xoff + col);
    const unsigned short h0 = f2bf(v.x), h1 = f2bf(v.y), h2 = f2bf(v.z), h3 = f2bf(v.w);
    const unsigned short l0 = f2bf(v.x - bf2f(h0)), l1 = f2bf(v.y - bf2f(h1));
    const unsigned short l2 = f2bf(v.z - bf2f(h2)), l3 = f2bf(v.w - bf2f(h3));
    u16x4 hv = {h0, h1, h2, h3}, lv = {l0, l1, l2, l3};
    *(u16x4*)(xh + xoff + col) = hv;
    *(u16x4*)(xl + xoff + col) = lv;
    tf[col + 0][row] = f2h(v.x); tf[col + 1][row] = f2h(v.y);
    tf[col + 2][row] = f2h(v.z); tf[col + 3][row] = f2h(v.w);
  }
  __syncthreads();
  const size_t toff = ((size_t)b * D_ + d0 + row) * T_ + t0;
#pragma unroll
  for (int c = 0; c < 4; ++c) {
    const int col = (cq << 4) + (c << 2);
    *(u16x4*)(xth + toff + col) = *(const u16x4*)&tf[row][col];
  }
}

// ---------------------------------------------------------------------------
// Scores: S = x.x^T, causal tiles, 3-product split-bf16 MFMA (err ~2^-17).
// 128x128 tile, BK=32, global_load_lds staging. XOR-swizzled LDS chunk slots
// (slot = q ^ (r&3) ^ ((r>>2)&1)) kill the ds_read_b128 bank conflicts; the
// permutation is applied on the GLOBAL source side since global_load_lds's
// LDS destination is forced to lane order.
// ---------------------------------------------------------------------------
__global__ __launch_bounds__(256) void scores_mfma(
    const unsigned short* __restrict__ xh, const unsigned short* __restrict__ xl,
    float* __restrict__ w) {
  const int ts = blockIdx.x, tt = blockIdx.y;
  if (ts > tt) return;
  const int b = blockIdx.z;
  const int t0 = tt << 7, s0 = ts << 7;
  __shared__ unsigned short Ah[128 * 32];
  __shared__ unsigned short Al[128 * 32];
  __shared__ unsigned short Bh[128 * 32];
  __shared__ unsigned short Bl[128 * 32];
  const int tid = threadIdx.x;
  const int lane = tid & 63, wv = tid >> 6;
  const int wr = (wv >> 1) << 6, wc = (wv & 1) << 6;
  const int quad = lane >> 4, r16 = lane & 15;
  const int swz = ((quad ^ (r16 & 3) ^ ((r16 >> 2) & 1)) << 3);  // shorts
  const size_t xb = (size_t)b * T_ * D_;

  f32x4 acc[4][4];
#pragma unroll
  for (int i = 0; i < 4; ++i)
#pragma unroll
    for (int j = 0; j < 4; ++j) acc[i][j] = (f32x4){0.f, 0.f, 0.f, 0.f};

  for (int k0 = 0; k0 < D_; k0 += 32) {
    __syncthreads();
#pragma unroll
    for (int i = 0; i < 2; ++i) {
      const int cc = (wv << 7) + (i << 6) + lane;  // 16B chunk id 0..511
      const int row = cc >> 2, q = cc & 3;
      const int gq = q ^ (row & 3) ^ ((row >> 2) & 1);
      const int ldsoff = (((wv << 7) + (i << 6)) << 3);  // wave-uniform, shorts
      const size_t ga = xb + (size_t)(t0 + row) * D_ + k0 + (gq << 3);
      const size_t gb = xb + (size_t)(s0 + row) * D_ + k0 + (gq << 3);
      gl2lds16(xh + ga, &Ah[ldsoff]);
      gl2lds16(xl + ga, &Al[ldsoff]);
      gl2lds16(xh + gb, &Bh[ldsoff]);
      gl2lds16(xl + gb, &Bl[ldsoff]);
    }
    __syncthreads();
    bf16x8 ah[4], al[4], bh[4], bl[4];
#pragma unroll
    for (int i = 0; i < 4; ++i) {
      const int ra = ((wr + (i << 4) + r16) << 5) + swz;
      const int rb = ((wc + (i << 4) + r16) << 5) + swz;
      ah[i] = *(const bf16x8*)&Ah[ra];
      al[i] = *(const bf16x8*)&Al[ra];
      bh[i] = *(const bf16x8*)&Bh[rb];
      bl[i] = *(const bf16x8*)&Bl[rb];
    }
#pragma unroll
    for (int i = 0; i < 4; ++i)
#pragma unroll
      for (int j = 0; j < 4; ++j) {
        acc[i][j] = __builtin_amdgcn_mfma_f32_16x16x32_bf16(ah[i], bh[j], acc[i][j], 0, 0, 0);
        acc[i][j] = __builtin_amdgcn_mfma_f32_16x16x32_bf16(ah[i], bl[j], acc[i][j], 0, 0, 0);
        acc[i][j] = __builtin_amdgcn_mfma_f32_16x16x32_bf16(al[i], bh[j], acc[i][j], 0, 0, 0);
      }
  }

  float* wb = w + (size_t)b * T_ * T_;
#pragma unroll
  for (int i = 0; i < 4; ++i)
#pragma unroll
    for (int j = 0; j < 4; ++j) {
      const int rr = t0 + wr + (i << 4) + (quad << 2);
      const int cc = s0 + wc + (j << 4) + r16;
#pragma unroll
      for (int rg = 0; rg < 4; ++rg)
        wb[(size_t)(rr + rg) * T_ + cc] = acc[i][j][rg];
    }
}

// ---------------------------------------------------------------------------
// Softmax: one wave per row, 32 vals/lane in registers, masked (causal-only)
// loads. Writes full fp32 rows (zeros above diag; row 0 uniform) and, if EMIT,
// fp16 W up to the 128-tile boundary (what av consumes). fp16 row 0 = zeros
// over s<128 (row 0 of out is produced by the row0 kernels instead).
// ---------------------------------------------------------------------------
template <bool EMIT>
__global__ __launch_bounds__(256) void softmax_kernel(float* __restrict__ w,
                                                      unsigned short* __restrict__ wf) {
  const int row = (blockIdx.x << 2) + (threadIdx.x >> 6);  // b*T + t
  const int t = row & (T_ - 1);
  const int lane = threadIdx.x & 63;
  float* wr = w + (size_t)row * T_;
  unsigned short* wfr = wf + (size_t)row * T_;

  if (t == 0) {
    const float u = 1.0f / 2048.0f;
#pragma unroll
    for (int k = 0; k < 32; ++k) {
      wr[lane + (k << 6)] = u;
      if (EMIT && k < 2) wfr[lane + (k << 6)] = 0;  // av reads row 0 only s<128
    }
    return;
  }

  const int kmax = ((t >> 7) + 1) << 1;  // 64-chunks covering the causal tiles
  float v[32];
  float m = -3.0e38f;
#pragma unroll
  for (int k = 0; k < 32; ++k) {
    const int s = lane + (k << 6);
    float val = -1.0e30f;
    if (s < t) val = wr[s];  // exec-masked load: upper half never fetched
    v[k] = val;
    m = fmaxf(m, val);
  }
#pragma unroll
  for (int off = 32; off; off >>= 1) m = fmaxf(m, __shfl_xor(m, off));

  float l = 0.f;
#pragma unroll
  for (int k = 0; k < 32; ++k) {
    v[k] = __expf(v[k] - m);  // masked slots -> exactly 0.0f
    l += v[k];
  }
#pragma unroll
  for (int off = 32; off; off >>= 1) l += __shfl_xor(l, off);
  const float inv = 1.0f / l;

#pragma unroll
  for (int k = 0; k < 32; ++k) {
    const float o = v[k] * inv;
    const int s = lane + (k << 6);
    wr[s] = o;
    if (EMIT && k < kmax) wfr[s] = f2h(o);
  }
}

// ---------------------------------------------------------------------------
// AV: out = W.x, single-product fp16 MFMA (W fp16 err 2^-12, x fp16 err 2^-11
// -> out err ~2^-10*sum(w|x|), better than the previous bf16-W path at half
// the MFMA work). 128x128 tile, BK=32, swizzled LDS. Causal k-range only
// (row 0 written later by row0 kernels). blockIdx.x encodes (td, tt_idx) so
// the 8 td-blocks sharing a W tile land on one XCD (linear%8 heuristic) and
// each XCD gets tt pair {k, 15-k} = identical total k-steps.
// ---------------------------------------------------------------------------
template <bool USE_WF16>
__global__ __launch_bounds__(256) void av_mfma(
    const float* __restrict__ w, const unsigned short* __restrict__ wf,
    const unsigned short* __restrict__ xth, float* __restrict__ out) {
  const int xid = blockIdx.x;
  const int td = xid >> 4;
  const int ti = xid & 15;
  const int tt = (ti < 8) ? ti : (23 - ti);  // XCD k gets {k, 15-k}
  const int b = blockIdx.z;
  const int t0 = tt << 7, d0 = td << 7;
  __shared__ unsigned short Aw[128 * 32];
  __shared__ unsigned short Bx[128 * 32];
  const int tid = threadIdx.x;
  const int lane = tid & 63, wv = tid >> 6;
  const int wr = (wv >> 1) << 6, wc = (wv & 1) << 6;
  const int quad = lane >> 4, r16 = lane & 15;
  const int swz = ((quad ^ (r16 & 3) ^ ((r16 >> 2) & 1)) << 3);
  const size_t xtb = (size_t)b * D_ * T_;
  const size_t wbase = (size_t)b * T_ * T_;
  const int smax = t0 + 128;

  f32x4 acc[4][4];
#pragma unroll
  for (int i = 0; i < 4; ++i)
#pragma unroll
    for (int j = 0; j < 4; ++j) acc[i][j] = (f32x4){0.f, 0.f, 0.f, 0.f};

  for (int s0 = 0; s0 < smax; s0 += 32) {
    __syncthreads();
    if (USE_WF16) {
#pragma unroll
      for (int i = 0; i < 2; ++i) {
        const int cc = (wv << 7) + (i << 6) + lane;
        const int row = cc >> 2, q = cc & 3;
        const int gq = q ^ (row & 3) ^ ((row >> 2) & 1);
        const int ldsoff = (((wv << 7) + (i << 6)) << 3);
        gl2lds16(wf + wbase + (size_t)(t0 + row) * T_ + s0 + (gq << 3), &Aw[ldsoff]);
      }
    } else {
      const int row = tid >> 1, half = tid & 1;
      const float* g = w + wbase + (size_t)(t0 + row) * T_ + s0 + (half << 4);
      const float4 v0 = ((const float4*)g)[0];
      const float4 v1 = ((const float4*)g)[1];
      const float4 v2 = ((const float4*)g)[2];
      const float4 v3 = ((const float4*)g)[3];
      const int sw = (row & 3) ^ ((row >> 2) & 1);
      u16x8 p0 = {f2h(v0.x), f2h(v0.y), f2h(v0.z), f2h(v0.w),
                  f2h(v1.x), f2h(v1.y), f2h(v1.z), f2h(v1.w)};
      u16x8 p1 = {f2h(v2.x), f2h(v2.y), f2h(v2.z), f2h(v2.w),
                  f2h(v3.x), f2h(v3.y), f2h(v3.z), f2h(v3.w)};
      *(u16x8*)&Aw[(row << 5) + ((((half << 1) | 0) ^ sw) << 3)] = p0;
      *(u16x8*)&Aw[(row << 5) + ((((half << 1) | 1) ^ sw) << 3)] = p1;
    }
#pragma unroll
    for (int i = 0; i < 2; ++i) {
      const int cc = (wv << 7) + (i << 6) + lane;
      const int row = cc >> 2, q = cc & 3;
      const int gq = q ^ (row & 3) ^ ((row >> 2) & 1);
      const int ldsoff = (((wv << 7) + (i << 6)) << 3);
      gl2lds16(xth + xtb + (size_t)(d0 + row) * T_ + s0 + (gq << 3), &Bx[ldsoff]);
    }
    __syncthreads();
    f16x8 a[4], bb[4];
#pragma unroll
    for (int i = 0; i < 4; ++i)
      a[i] = *(const f16x8*)&Aw[((wr + (i << 4) + r16) << 5) + swz];
#pragma unroll
    for (int j = 0; j < 4; ++j)
      bb[j] = *(const f16x8*)&Bx[((wc + (j << 4) + r16) << 5) + swz];
#pragma unroll
    for (int i = 0; i < 4; ++i)
#pragma unroll
      for (int j = 0; j < 4; ++j)
        acc[i][j] = __builtin_amdgcn_mfma_f32_16x16x32_f16(a[i], bb[j], acc[i][j], 0, 0, 0);
  }

  float* ob = out + (size_t)b * T_ * D_;
#pragma unroll
  for (int i = 0; i < 4; ++i)
#pragma unroll
    for (int j = 0; j < 4; ++j) {
      const int rr = t0 + wr + (i << 4) + (quad << 2);
      const int cc = d0 + wc + (j << 4) + r16;
#pragma unroll
      for (int rg = 0; rg < 4; ++rg)
        ob[(size_t)(rr + rg) * D_ + cc] = acc[i][j][rg];
    }
}

// ---------------------------------------------------------------------------
// Row 0 of out = mean over all T rows of x (uniform weights, faithful to ref).
// ---------------------------------------------------------------------------
__global__ __launch_bounds__(256) void row0_partial(const float* __restrict__ x,
                                                    float* __restrict__ part) {
  const int tc = blockIdx.x, b = blockIdx.y;
  const int tid = threadIdx.x;
  const float* xb = x + ((size_t)b * T_ + (tc << 8)) * D_;
  float4 s = {0.f, 0.f, 0.f, 0.f};
#pragma unroll 4
  for (int r = 0; r < 256; ++r) {
    const float4 v = *(const float4*)(xb + (size_t)r * D_ + (tid << 2));
    s.x += v.x; s.y += v.y; s.z += v.z; s.w += v.w;
  }
  *(float4*)(part + ((size_t)((b << 3) + tc)) * D_ + (tid << 2)) = s;
}

__global__ __launch_bounds__(256) void row0_reduce(const float* __restrict__ part,
                                                   float* __restrict__ out) {
  const int b = blockIdx.x;
  const int tid = threadIdx.x;
  float4 s = {0.f, 0.f, 0.f, 0.f};
#pragma unroll
  for (int p = 0; p < 8; ++p) {
    const float4 v = *(const float4*)(part + ((size_t)((b << 3) + p)) * D_ + (tid << 2));
    s.x += v.x; s.y += v.y; s.z += v.z; s.w += v.w;
  }
  const float sc = 1.0f / 2048.0f;
  float4 o = {s.x * sc, s.y * sc, s.z * sc, s.w * sc};
  *(float4*)(out + (size_t)b * T_ * D_ + (tid << 2)) = o;  // row t=0
}

// ---------------------------------------------------------------------------
extern "C" void kernel_launch(void* const* d_in, const int* in_sizes, int n_in,
                              void* d_out, int out_size, void* d_ws, size_t ws_size,
                              hipStream_t stream) {
  const float* x = (const float*)d_in[0];
  float* att_vec = (float*)d_out;                   // [B,T,D] output 0
  float* w = (float*)d_out + (size_t)B_ * T_ * D_;  // [B,T,T] output 1

  // xh/xl (bf16, row-major) staged in the att_vec region; consumed by scores
  // before av/row0 overwrite it.
  unsigned short* xh = (unsigned short*)att_vec;
  unsigned short* xl = xh + (size_t)B_ * T_ * D_;
  // workspace: xT fp16 (33.5 MB) + W fp16 (67 MB) + row0 partials (256 KB)
  const size_t xthN = (size_t)B_ * D_ * T_;
  const size_t wfN = (size_t)B_ * T_ * T_;
  unsigned short* xth = (unsigned short*)d_ws;
  unsigned short* wf16 = xth + xthN;
  const size_t need = xthN * 2 + wfN * 2 + (size_t)64 * D_ * 4;
  const bool use_wf16 = (ws_size >= need);
  float* part = use_wf16 ? (float*)(wf16 + wfN) : (float*)(xth + xthN);

  prep_kernel<<<dim3(D_ / 64, T_ / 64, B_), 256, 0, stream>>>(x, xh, xl, xth);
  scores_mfma<<<dim3(16, 16, B_), 256, 0, stream>>>(xh, xl, w);
  if (use_wf16) {
    softmax_kernel<true><<<dim3(B_ * T_ / 4), 256, 0, stream>>>(w, wf16);
    av_mfma<true><<<dim3(128, 1, B_), 256, 0, stream>>>(w, wf16, xth, att_vec);
  } else {
    softmax_kernel<false><<<dim3(B_ * T_ / 4), 256, 0, stream>>>(w, wf16);
    av_mfma<false><<<dim3(128, 1, B_), 256, 0, stream>>>(w, wf16, xth, att_vec);
  }
  row0_partial<<<dim3(8, B_), 256, 0, stream>>>(x, part);
  row0_reduce<<<dim3(B_), 256, 0, stream>>>(part, att_vec);
}